// Round 13
// baseline (65.799 us; speedup 1.0000x reference)
//
#include <hip/hip_runtime.h>
#include <hip/hip_cooperative_groups.h>
#include <math.h>

namespace cg = cooperative_groups;

#define NFACE 512
#define NVERT 642
#define NPIX  (256 * 256)
#define DXS   (2.0f / 256.0f)

// Camera constants (input-independent, folded from the reference):
#define EYEX 2.732f
#define EYEZ (-1.6728675276352845e-16f)
#define CC0  (6.123233995736766e-17f)

// Single cooperative dispatch. 256 blocks x 256 threads, block = 16x16 tile,
// wave = one 8x8 quadrant; LISTS ARE SPLIT BY VERTICAL HALF (waves 0,1 = top
// 8 rows, waves 2,3 = bottom 8 rows). Pass A: 2 faces/thread, exact corner-
// bound classify per half (B-extremes shared), per-half depth prune
// (M_h = min over half-full faces of dmax+md; dmin-md > M_h can never win
// the argmin in that half — removes only reference-losing faces).
// Pass B: append DENSE records (no index indirection — keeps LDS loads
// sequentially pipelinable, the R12 lesson): partials at slots 0.. of
// p0/p1/pd, fulls at slots 511.. downward of p0. fcnt+pcnt <= 512 by
// construction (a face enters each half at most once) -> no overflow.
// Pass C: per-pixel argmin: fulls = 1 x b128 (depth plane only), partials =
// b128+b128+b64. Pack (depth_bits & ~511) | face, u32 min — order-invariant,
// ties -> smaller face index (matches jnp.argmin first-index).
// Epilogue recomputes the winner's barycentric coefs from sverts.
// Finish: per-block sums -> d_ws (plain store), grid.sync(), block 0 reduces.
// Records: w_k = A_k*Py+B_k*Px+C_k (== ref w_k/denom, sign folded),
// w2 = 1-w0-w1; depth = DA*Py+DB*Px+DC; inside => depth>0 (camera z>1.73).
__global__ __launch_bounds__(256) void render_loss(
    const float* __restrict__ verts,   // (642,3)
    const int*   __restrict__ faces,   // (512,3)
    const float* __restrict__ tex,     // (512,4,4,4,3)
    const float* __restrict__ ref,     // (3,256,256)
    float* __restrict__ bsum,          // (256) per-block partials in d_ws
    float* __restrict__ out)           // scalar
{
    __shared__ float  sverts[NVERT * 3];
    __shared__ float4 p0[2][NFACE];      // partial: A0,B0,C0,A1 | full: DA,DB,DC,fid
    __shared__ float4 p1[2][NFACE];      // partial: B1,C1,DA,DB
    __shared__ float2 pd[2][NFACE];      // partial: DC,fid
    __shared__ int fcnt[2], pcnt[2];
    __shared__ unsigned Mu[2];
    __shared__ float wsum[4];

    int tid  = threadIdx.x;
    int lane = tid & 63;
    int w    = tid >> 6;
    if (tid < 2) { fcnt[tid] = 0; pcnt[tid] = 0; Mu[tid] = 0x7f800000u; }

    for (int k = tid; k < NVERT * 3; k += 256) sverts[k] = verts[k];
    __syncthreads();

    int tileX = (blockIdx.x & 15) << 4;
    int tileY = (blockIdx.x >> 4) << 4;
    float xlo = (tileX + 0.5f)  * DXS - 1.0f;
    float xhi = (tileX + 15.5f) * DXS - 1.0f;
    float yhis[2], ylos[2];
    yhis[0] = 1.0f - (tileY + 0.5f)  * DXS;   // top half: rows 0..7
    ylos[0] = 1.0f - (tileY + 7.5f)  * DXS;
    yhis[1] = 1.0f - (tileY + 8.5f)  * DXS;   // bottom half: rows 8..15
    ylos[1] = 1.0f - (tileY + 15.5f) * DXS;
    float tylo = ylos[1], tyhi = yhis[0];

    // ---- pass A: setup + per-half classify (2 faces/thread, regs) ----
    float rc[2][9];          // A0,B0,C0,A1,B1,C1,DA,DB,DC
    float rdm[2][2];         // dmin - md per (it,half)
    unsigned cls = 0;        // 2 bits per (it*2+h): 1=full, 2=partial
#pragma unroll
    for (int it = 0; it < 2; ++it) {
        int f = tid + it * 256;
        float vx[3], vy[3], vz[3];
#pragma unroll
        for (int k = 0; k < 3; ++k) {
            int vi = faces[f * 3 + k];
            float px = sverts[vi * 3 + 0];
            float py = sverts[vi * 3 + 1];
            float pz = sverts[vi * 3 + 2];
            float dx = px - EYEX;
            float dz = pz - EYEZ;
            vx[k] = CC0 * dx + dz;
            vy[k] = py;
            vz[k] = -dx + CC0 * dz;
        }
        float ax = vx[0], ay = vy[0];
        float bx = vx[1], by = vy[1];
        float cx = vx[2], cy = vy[2];
        float denom = (bx - ax) * (cy - ay) - (by - ay) * (cx - ax);
        if (fabsf(denom) <= 1e-8f) continue;     // degenerate: never visible

        float si = 1.0f / denom;                 // sign folded
        float e0x = cx - bx, e0y = cy - by;
        float e1x = ax - cx, e1y = ay - cy;
        float A0 = e0x * si, B0 = -e0y * si, C0 = (e0y * bx - e0x * by) * si;
        float A1 = e1x * si, B1 = -e1y * si, C1 = (e1y * cx - e1x * cy) * si;
        float A2 = -(A0 + A1), B2 = -(B0 + B1), C2 = 1.0f - C0 - C1;
        float DA = A0 * vz[0] + A1 * vz[1] + A2 * vz[2];
        float DB = B0 * vz[0] + B1 * vz[1] + B2 * vz[2];
        float DC = C0 * vz[0] + C1 * vz[1] + C2 * vz[2];
        rc[it][0] = A0; rc[it][1] = B0; rc[it][2] = C0;
        rc[it][3] = A1; rc[it][4] = B1; rc[it][5] = C1;
        rc[it][6] = DA; rc[it][7] = DB; rc[it][8] = DC;

        // bbox pre-reject vs whole tile
        float bxmn = fminf(fminf(ax, bx), cx), bxmx = fmaxf(fmaxf(ax, bx), cx);
        float bymn = fminf(fminf(ay, by), cy), bymx = fmaxf(fmaxf(ay, by), cy);
        if ((bxmn > xhi + 1e-5f) | (bxmx < tylo - 1e-5f) |
            (bymn > tyhi + 1e-5f) | (bymx < tylo - 1e-5f) |
            (bxmx < xlo - 1e-5f) | (bymn > tyhi + 1e-5f)) { /* keep simple */ }
        if ((bxmn > xhi + 1e-5f) | (bxmx < xlo - 1e-5f) |
            (bymn > tyhi + 1e-5f) | (bymx < tylo - 1e-5f)) continue;

        float As[3] = {A0, A1, A2}, Bs[3] = {B0, B1, B2}, Cs[3] = {C0, C1, C2};
        float bmx[3], bmn[3], mg[3];
#pragma unroll
        for (int k = 0; k < 3; ++k) {
            float u1 = Bs[k] * xlo, u2 = Bs[k] * xhi;
            bmx[k] = fmaxf(u1, u2);
            bmn[k] = fminf(u1, u2);
            mg[k]  = (fabsf(As[k]) + fabsf(Bs[k]) + fabsf(Cs[k])) * 4e-6f;
        }
        float dbx = fmaxf(DB * xlo, DB * xhi);
        float dbn = fminf(DB * xlo, DB * xhi);
        float md  = (fabsf(DA) + fabsf(DB) + fabsf(DC)) * 4e-6f + 1e-4f;

#pragma unroll
        for (int h = 0; h < 2; ++h) {
            bool rej = false, full = true;
#pragma unroll
            for (int k = 0; k < 3; ++k) {
                float t1 = As[k] * ylos[h], t2 = As[k] * yhis[h];
                float wmx = fmaxf(t1, t2) + bmx[k] + Cs[k];
                float wmn = fminf(t1, t2) + bmn[k] + Cs[k];
                rej  = rej  | (wmx < -mg[k]);
                full = full & (wmn >  mg[k]);
            }
            if (rej) continue;
            float t1 = DA * ylos[h], t2 = DA * yhis[h];
            float dmx = fmaxf(t1, t2) + dbx + DC;
            float dmn = fminf(t1, t2) + dbn + DC;
            rdm[it][h] = dmn - md;
            cls |= (full ? 1u : 2u) << (2 * (it * 2 + h));
            if (full) atomicMin(&Mu[h], __float_as_uint(dmx + md));
        }
    }
    __syncthreads();

    // ---- pass B: depth-pruned dense append ----
    float Mh[2] = { __uint_as_float(Mu[0]), __uint_as_float(Mu[1]) };
#pragma unroll
    for (int it = 0; it < 2; ++it) {
        float fidf = __uint_as_float((unsigned)(tid + it * 256));
#pragma unroll
        for (int h = 0; h < 2; ++h) {
            unsigned c = (cls >> (2 * (it * 2 + h))) & 3u;
            if (c == 0u || rdm[it][h] > Mh[h]) continue;
            if (c == 1u) {
                int s = atomicAdd(&fcnt[h], 1);
                p0[h][511 - s] = make_float4(rc[it][6], rc[it][7], rc[it][8], fidf);
            } else {
                int s = atomicAdd(&pcnt[h], 1);
                p0[h][s] = make_float4(rc[it][0], rc[it][1], rc[it][2], rc[it][3]);
                p1[h][s] = make_float4(rc[it][4], rc[it][5], rc[it][6], rc[it][7]);
                pd[h][s] = make_float2(rc[it][8], fidf);
            }
        }
    }
    __syncthreads();

    // ---- pass C: per-pixel argmin over this wave's half lists ----
    int h  = w >> 1;
    int fc = fcnt[h], pc = pcnt[h];
    int i = tileX + ((w & 1) << 3) + (lane & 7);
    int j = tileY + (h << 3) + (lane >> 3);
    float Px = (i + 0.5f) * DXS - 1.0f;
    float Py = 1.0f - (j + 0.5f) * DXS;

    unsigned best = 0xFFFFFFFFu;
    int k = 0;
    for (; k + 4 <= fc; k += 4) {
        float4 ra = p0[h][511 - k], rb = p0[h][510 - k];
        float4 rc4 = p0[h][509 - k], rd = p0[h][508 - k];
        float da = fmaf(ra.x, Py, fmaf(ra.y, Px, ra.z));
        float db = fmaf(rb.x, Py, fmaf(rb.y, Px, rb.z));
        float dc = fmaf(rc4.x, Py, fmaf(rc4.y, Px, rc4.z));
        float dd = fmaf(rd.x, Py, fmaf(rd.y, Px, rd.z));
        unsigned ca = (__float_as_uint(da) & 0xFFFFFE00u) | __float_as_uint(ra.w);
        unsigned cb = (__float_as_uint(db) & 0xFFFFFE00u) | __float_as_uint(rb.w);
        unsigned cc = (__float_as_uint(dc) & 0xFFFFFE00u) | __float_as_uint(rc4.w);
        unsigned cd = (__float_as_uint(dd) & 0xFFFFFE00u) | __float_as_uint(rd.w);
        ca = ca < cb ? ca : cb;
        cc = cc < cd ? cc : cd;
        ca = ca < cc ? ca : cc;
        best = best < ca ? best : ca;
    }
    for (; k < fc; ++k) {
        float4 r = p0[h][511 - k];
        float dep = fmaf(r.x, Py, fmaf(r.y, Px, r.z));
        unsigned cand = (__float_as_uint(dep) & 0xFFFFFE00u) | __float_as_uint(r.w);
        best = best < cand ? best : cand;
    }
    k = 0;
    for (; k + 2 <= pc; k += 2) {
        float4 a0 = p0[h][k], a1 = p1[h][k];
        float2 ad = pd[h][k];
        float4 b0 = p0[h][k + 1], b1 = p1[h][k + 1];
        float2 bd = pd[h][k + 1];
        float aw0 = fmaf(a0.x, Py, fmaf(a0.y, Px, a0.z));
        float aw1 = fmaf(a0.w, Py, fmaf(a1.x, Px, a1.y));
        float aw2 = 1.0f - aw0 - aw1;
        float adp = fmaf(a1.z, Py, fmaf(a1.w, Px, ad.x));
        float amn = fminf(fminf(aw0, aw1), aw2);
        unsigned ac = (__float_as_uint(adp) & 0xFFFFFE00u) | __float_as_uint(ad.y);
        ac = (amn >= 0.f) ? ac : 0xFFFFFFFFu;
        float bw0 = fmaf(b0.x, Py, fmaf(b0.y, Px, b0.z));
        float bw1 = fmaf(b0.w, Py, fmaf(b1.x, Px, b1.y));
        float bw2 = 1.0f - bw0 - bw1;
        float bdp = fmaf(b1.z, Py, fmaf(b1.w, Px, bd.x));
        float bmn = fminf(fminf(bw0, bw1), bw2);
        unsigned bc = (__float_as_uint(bdp) & 0xFFFFFE00u) | __float_as_uint(bd.y);
        bc = (bmn >= 0.f) ? bc : 0xFFFFFFFFu;
        ac = ac < bc ? ac : bc;
        best = best < ac ? best : ac;
    }
    for (; k < pc; ++k) {
        float4 q0 = p0[h][k], q1 = p1[h][k];
        float2 qd = pd[h][k];
        float w0  = fmaf(q0.x, Py, fmaf(q0.y, Px, q0.z));
        float w1  = fmaf(q0.w, Py, fmaf(q1.x, Px, q1.y));
        float w2  = 1.0f - w0 - w1;
        float dep = fmaf(q1.z, Py, fmaf(q1.w, Px, qd.x));
        float mn  = fminf(fminf(w0, w1), w2);
        unsigned cand = (__float_as_uint(dep) & 0xFFFFFE00u) | __float_as_uint(qd.y);
        cand = (mn >= 0.f) ? cand : 0xFFFFFFFFu;
        best = best < cand ? best : cand;
    }

    // ---- epilogue: recompute winner's coefs from sverts ----
    int p = j * 256 + i;
    float col0 = 0.f, col1 = 0.f, col2 = 0.f;
    if (best != 0xFFFFFFFFu) {
        int bf = (int)(best & 511u);
        float vx[3], vy[3], vz_;
#pragma unroll
        for (int kk = 0; kk < 3; ++kk) {
            int vi = faces[bf * 3 + kk];
            float px = sverts[vi * 3 + 0];
            float py = sverts[vi * 3 + 1];
            float pz = sverts[vi * 3 + 2];
            float dx = px - EYEX;
            float dz = pz - EYEZ;
            vx[kk] = CC0 * dx + dz;
            vy[kk] = py;
        }
        (void)vz_;
        float ax = vx[0], ay = vy[0];
        float bx = vx[1], by = vy[1];
        float cx = vx[2], cy = vy[2];
        float denom = (bx - ax) * (cy - ay) - (by - ay) * (cx - ax);
        float si = 1.0f / denom;
        float e0x = cx - bx, e0y = cy - by;
        float e1x = ax - cx, e1y = ay - cy;
        float A0 = e0x * si, B0 = -e0y * si, C0 = (e0y * bx - e0x * by) * si;
        float A1 = e1x * si, B1 = -e1y * si, C1 = (e1y * cx - e1x * cy) * si;
        float w0 = fmaf(A0, Py, fmaf(B0, Px, C0));
        float w1 = fmaf(A1, Py, fmaf(B1, Px, C1));
        float w2 = 1.0f - w0 - w1;
        int t0 = (int)rintf(w0 * 3.0f); t0 = t0 < 0 ? 0 : (t0 > 3 ? 3 : t0);
        int t1 = (int)rintf(w1 * 3.0f); t1 = t1 < 0 ? 0 : (t1 > 3 ? 3 : t1);
        int t2 = (int)rintf(w2 * 3.0f); t2 = t2 < 0 ? 0 : (t2 > 3 ? 3 : t2);
        const float* tp = tex + ((((bf * 4 + t0) * 4 + t1) * 4 + t2) * 3);
        col0 = tanhf(tp[0]);
        col1 = tanhf(tp[1]);
        col2 = tanhf(tp[2]);
    }
    float r0 = ref[0 * NPIX + p];
    float r1 = ref[1 * NPIX + p];
    float r2 = ref[2 * NPIX + p];
    float e0 = col0 - r0, e1 = col1 - r1, e2 = col2 - r2;
    float loss = e0 * e0 + e1 * e1 + e2 * e2;

    // ---- block reduce -> plain store -> grid sync -> block 0 reduces ----
    for (int off = 32; off > 0; off >>= 1)
        loss += __shfl_down(loss, off, 64);
    if (lane == 0) wsum[w] = loss;
    __syncthreads();
    if (tid == 0)
        bsum[blockIdx.x] = wsum[0] + wsum[1] + wsum[2] + wsum[3];
    __threadfence();

    cg::this_grid().sync();

    if (blockIdx.x == 0) {
        float v = bsum[tid];
        for (int off = 32; off > 0; off >>= 1)
            v += __shfl_down(v, off, 64);
        if (lane == 0) wsum[w] = v;
        __syncthreads();
        if (tid == 0) out[0] = wsum[0] + wsum[1] + wsum[2] + wsum[3];
    }
}

extern "C" void kernel_launch(void* const* d_in, const int* in_sizes, int n_in,
                              void* d_out, int out_size, void* d_ws, size_t ws_size,
                              hipStream_t stream) {
    const float* verts = (const float*)d_in[0];
    const float* tex   = (const float*)d_in[1];
    const float* ref   = (const float*)d_in[2];
    const int*   faces = (const int*)d_in[3];
    float* out  = (float*)d_out;
    float* bsum = (float*)d_ws;     // 256 floats

    void* args[] = { (void*)&verts, (void*)&faces, (void*)&tex, (void*)&ref,
                     (void*)&bsum, (void*)&out };
    hipLaunchCooperativeKernel((const void*)render_loss, dim3(256), dim3(256),
                               args, 0, stream);
}

// Round 14
// 17.472 us; speedup vs baseline: 3.7659x; 3.7659x over previous
//
#include <hip/hip_runtime.h>
#include <math.h>

#define NFACE 512
#define NVERT 642
#define NPIX  (256 * 256)
#define DXS   (2.0f / 256.0f)

// Camera constants (input-independent, folded from the reference):
#define EYEX 2.732f
#define EYEZ (-1.6728675276352845e-16f)
#define CC0  (6.123233995736766e-17f)

// Fused renderer, 256 blocks x 256 threads, block = 16x16 tile (R10 skeleton).
// Phase 1: per-face exact corner-bound classify (reject/full/partial) +
// tile-level depth prune (M = min over full faces of dmax+md; dmin-md > M
// can never win the argmin — removes only reference-losing faces).
// Phase 2 (NEW): list split ACROSS waves (wave w takes entries k%4==w),
// each wave covers ALL 256 pixels (4 px/thread, 4 accumulators) -> each
// record's 3 ds_read_b128 amortize over 4 pixels and are issued by exactly
// one wave: 4x fewer LDS instructions through the CU-shared pipe.
// Merge: per-wave packs -> [4][256] LDS (2-way bank alias = free), u32-min.
// Pack (depth_bits & ~511) | face, u32 min — order/partition-invariant,
// ties -> smaller face index (matches jnp.argmin first-index).
// Records: w_k = A_k*Py+B_k*Px+C_k (== ref w_k/denom, sign folded),
// w2 = 1-w0-w1; depth = DA*Py+DB*Px+DC; inside => depth>0 (camera z>1.73).
__global__ __launch_bounds__(256) void render_loss(
    const float* __restrict__ verts,   // (642,3)
    const int*   __restrict__ faces,   // (512,3)
    const float* __restrict__ tex,     // (512,4,4,4,3)
    const float* __restrict__ ref,     // (3,256,256)
    float* __restrict__ out)           // scalar (pre-zeroed)
{
    __shared__ float  sverts[NVERT * 3];
    __shared__ float4 sf0[NFACE];        // A0,B0,C0,A1   (epilogue)
    __shared__ float4 sf1[NFACE];        // B1,C1,DA,DB   (epilogue)
    __shared__ float4 flist[NFACE];      // full: DA,DB,DC,fid
    __shared__ float4 pl0[NFACE];        // partial: A0,B0,C0,A1
    __shared__ float4 pl1[NFACE];        // partial: B1,C1,DA,DB
    __shared__ float2 pld[NFACE];        // partial: DC,fid
    __shared__ unsigned marr[4][256];    // per-wave per-pixel packs
    __shared__ int   fcnt, pcnt;
    __shared__ unsigned Mu;
    __shared__ float wsum[4];

    int tid = threadIdx.x;
    if (tid == 0) { fcnt = 0; pcnt = 0; Mu = 0x7f800000u; }

    for (int k = tid; k < NVERT * 3; k += 256) sverts[k] = verts[k];
    __syncthreads();

    int tileX = (blockIdx.x & 15) << 4;
    int tileY = (blockIdx.x >> 4) << 4;
    float xlo = (tileX + 0.5f)  * DXS - 1.0f;
    float xhi = (tileX + 15.5f) * DXS - 1.0f;
    float yhi = 1.0f - (tileY + 0.5f)  * DXS;
    float ylo = 1.0f - (tileY + 15.5f) * DXS;

    // ---- phase 1a: setup + classify (2 faces/thread, results in regs) ----
    float rc[2][9];      // A0,B0,C0,A1,B1,C1,DA,DB,DC
    int   rcls[2];       // 0=rejected, 1=full, 2=partial
    float rdmn[2];       // dmin - margin
#pragma unroll
    for (int it = 0; it < 2; ++it) {
        int f = tid + it * 256;
        rcls[it] = 0;
        float vx[3], vy[3], vz[3];
#pragma unroll
        for (int k = 0; k < 3; ++k) {
            int vi = faces[f * 3 + k];
            float px = sverts[vi * 3 + 0];
            float py = sverts[vi * 3 + 1];
            float pz = sverts[vi * 3 + 2];
            float dx = px - EYEX;
            float dz = pz - EYEZ;
            vx[k] = CC0 * dx + dz;
            vy[k] = py;
            vz[k] = -dx + CC0 * dz;
        }
        float ax = vx[0], ay = vy[0];
        float bx = vx[1], by = vy[1];
        float cx = vx[2], cy = vy[2];
        float denom = (bx - ax) * (cy - ay) - (by - ay) * (cx - ax);
        if (fabsf(denom) <= 1e-8f) continue;      // degenerate

        float si = 1.0f / denom;                  // sign folded
        float e0x = cx - bx, e0y = cy - by;
        float e1x = ax - cx, e1y = ay - cy;
        float e2x = bx - ax, e2y = by - ay;
        float A0 = e0x * si, B0 = -e0y * si, C0 = (e0y * bx - e0x * by) * si;
        float A1 = e1x * si, B1 = -e1y * si, C1 = (e1y * cx - e1x * cy) * si;
        float A2 = -(A0 + A1), B2 = -(B0 + B1), C2 = 1.0f - C0 - C1;
        float DA = A0 * vz[0] + A1 * vz[1] + A2 * vz[2];
        float DB = B0 * vz[0] + B1 * vz[1] + B2 * vz[2];
        float DC = C0 * vz[0] + C1 * vz[1] + C2 * vz[2];

        sf0[f] = make_float4(A0, B0, C0, A1);
        sf1[f] = make_float4(B1, C1, DA, DB);

        // bbox pre-reject
        float bxmn = fminf(fminf(ax, bx), cx), bxmx = fmaxf(fmaxf(ax, bx), cx);
        float bymn = fminf(fminf(ay, by), cy), bymx = fmaxf(fmaxf(ay, by), cy);
        if ((bxmn > xhi + 1e-5f) | (bxmx < xlo - 1e-5f) |
            (bymn > yhi + 1e-5f) | (bymx < ylo - 1e-5f)) continue;

        // exact corner bounds per edge, magnitude-scaled margins
        float wmx[3], wmn[3], mg[3];
        float As[3] = {A0, A1, A2}, Bs[3] = {B0, B1, B2}, Cs[3] = {C0, C1, C2};
#pragma unroll
        for (int k = 0; k < 3; ++k) {
            float t1 = As[k] * ylo, t2 = As[k] * yhi;
            float u1 = Bs[k] * xlo, u2 = Bs[k] * xhi;
            wmx[k] = fmaxf(t1, t2) + fmaxf(u1, u2) + Cs[k];
            wmn[k] = fminf(t1, t2) + fminf(u1, u2) + Cs[k];
            mg[k]  = (fabsf(As[k]) + fabsf(Bs[k]) + fabsf(Cs[k])) * 2e-6f;
        }
        if ((wmx[0] < -mg[0]) | (wmx[1] < -mg[1]) | (wmx[2] < -mg[2])) continue;
        bool full = (wmn[0] > mg[0]) & (wmn[1] > mg[1]) & (wmn[2] > mg[2]);

        // depth corner range + margin
        float t1 = DA * ylo, t2 = DA * yhi;
        float u1 = DB * xlo, u2 = DB * xhi;
        float dmx = fmaxf(t1, t2) + fmaxf(u1, u2) + DC;
        float dmn = fminf(t1, t2) + fminf(u1, u2) + DC;
        float md  = (fabsf(DA) + fabsf(DB) + fabsf(DC)) * 2e-6f + 1e-4f;
        rdmn[it] = dmn - md;
        rcls[it] = full ? 1 : 2;
        rc[it][0] = A0; rc[it][1] = B0; rc[it][2] = C0;
        rc[it][3] = A1; rc[it][4] = B1; rc[it][5] = C1;
        rc[it][6] = DA; rc[it][7] = DB; rc[it][8] = DC;
        if (full) atomicMin(&Mu, __float_as_uint(dmx + md));
    }
    __syncthreads();

    // ---- phase 1b: depth-pruned dense append ----
    float M = __uint_as_float(Mu);
#pragma unroll
    for (int it = 0; it < 2; ++it) {
        if (rcls[it] == 0 || rdmn[it] > M) continue;
        int f = tid + it * 256;
        float fb = __uint_as_float((unsigned)f);
        if (rcls[it] == 1) {
            int s = atomicAdd(&fcnt, 1);
            flist[s] = make_float4(rc[it][6], rc[it][7], rc[it][8], fb);
        } else {
            int s = atomicAdd(&pcnt, 1);
            pl0[s] = make_float4(rc[it][0], rc[it][1], rc[it][2], rc[it][3]);
            pl1[s] = make_float4(rc[it][4], rc[it][5], rc[it][6], rc[it][7]);
            pld[s] = make_float2(rc[it][8], fb);
        }
    }
    __syncthreads();
    int fc = fcnt, pc = pcnt;

    // ---- phase 2: wave w takes list entries k%4==w, covers ALL 256 px ----
    int lane = tid & 63;
    int w    = tid >> 6;
    int col   = lane & 15;
    int rbase = (lane >> 4) << 2;                 // rows rbase..rbase+3
    float Px  = (tileX + col + 0.5f) * DXS - 1.0f;
    float Py0 = 1.0f - (tileY + rbase + 0.5f) * DXS;
    // Py_q = Py0 - q*DXS

    unsigned pk0 = 0xFFFFFFFFu, pk1 = 0xFFFFFFFFu;
    unsigned pk2 = 0xFFFFFFFFu, pk3 = 0xFFFFFFFFu;

#pragma unroll 2
    for (int k = w; k < fc; k += 4) {
        float4 r = flist[k];
        float td = fmaf(r.y, Px, r.z);            // DB*Px + DC
        float d0 = fmaf(r.x, Py0, td);
        float d1 = fmaf(r.x, Py0 - DXS, td);
        float d2 = fmaf(r.x, Py0 - 2.0f * DXS, td);
        float d3 = fmaf(r.x, Py0 - 3.0f * DXS, td);
        unsigned fb = __float_as_uint(r.w);
        unsigned c0 = (__float_as_uint(d0) & 0xFFFFFE00u) | fb;
        unsigned c1 = (__float_as_uint(d1) & 0xFFFFFE00u) | fb;
        unsigned c2 = (__float_as_uint(d2) & 0xFFFFFE00u) | fb;
        unsigned c3 = (__float_as_uint(d3) & 0xFFFFFE00u) | fb;
        pk0 = pk0 < c0 ? pk0 : c0;
        pk1 = pk1 < c1 ? pk1 : c1;
        pk2 = pk2 < c2 ? pk2 : c2;
        pk3 = pk3 < c3 ? pk3 : c3;
    }

#pragma unroll 2
    for (int k = w; k < pc; k += 4) {
        float4 q0 = pl0[k];
        float4 q1 = pl1[k];
        float2 qd = pld[k];
        float t0 = fmaf(q0.y, Px, q0.z);          // B0*Px + C0
        float t1 = fmaf(q1.x, Px, q1.y);          // B1*Px + C1
        float td = fmaf(q1.w, Px, qd.x);          // DB*Px + DC
        unsigned fb = __float_as_uint(qd.y);
#pragma unroll
        for (int q = 0; q < 4; ++q) {
            float Py = Py0 - (float)q * DXS;
            float w0 = fmaf(q0.x, Py, t0);
            float w1 = fmaf(q0.w, Py, t1);
            float w2 = 1.0f - w0 - w1;
            float dp = fmaf(q1.z, Py, td);
            float mn = fminf(fminf(w0, w1), w2);
            unsigned cd = (__float_as_uint(dp) & 0xFFFFFE00u) | fb;
            cd = (mn >= 0.f) ? cd : 0xFFFFFFFFu;
            if (q == 0) pk0 = pk0 < cd ? pk0 : cd;
            if (q == 1) pk1 = pk1 < cd ? pk1 : cd;
            if (q == 2) pk2 = pk2 < cd ? pk2 : cd;
            if (q == 3) pk3 = pk3 < cd ? pk3 : cd;
        }
    }

    // ---- merge across waves ----
    marr[w][(rbase + 0) * 16 + col] = pk0;
    marr[w][(rbase + 1) * 16 + col] = pk1;
    marr[w][(rbase + 2) * 16 + col] = pk2;
    marr[w][(rbase + 3) * 16 + col] = pk3;
    __syncthreads();
    unsigned best = marr[0][tid];
    unsigned m1 = marr[1][tid];
    unsigned m2 = marr[2][tid];
    unsigned m3 = marr[3][tid];
    best = best < m1 ? best : m1;
    best = best < m2 ? best : m2;
    best = best < m3 ? best : m3;

    // ---- phase 3: epilogue (thread tid owns pixel (tid&15, tid>>4)) ----
    int i = tileX + (tid & 15);
    int j = tileY + (tid >> 4);
    float Pxe = (i + 0.5f) * DXS - 1.0f;
    float Pye = 1.0f - (j + 0.5f) * DXS;
    int p = j * 256 + i;
    float col0 = 0.f, col1 = 0.f, col2 = 0.f;
    if (best != 0xFFFFFFFFu) {
        int bf = (int)(best & 511u);
        float4 q0 = sf0[bf];
        float4 q1 = sf1[bf];
        float w0 = fmaf(q0.x, Pye, fmaf(q0.y, Pxe, q0.z));
        float w1 = fmaf(q0.w, Pye, fmaf(q1.x, Pxe, q1.y));
        float w2 = 1.0f - w0 - w1;
        int t0 = (int)rintf(w0 * 3.0f); t0 = t0 < 0 ? 0 : (t0 > 3 ? 3 : t0);
        int t1 = (int)rintf(w1 * 3.0f); t1 = t1 < 0 ? 0 : (t1 > 3 ? 3 : t1);
        int t2 = (int)rintf(w2 * 3.0f); t2 = t2 < 0 ? 0 : (t2 > 3 ? 3 : t2);
        const float* tp = tex + ((((bf * 4 + t0) * 4 + t1) * 4 + t2) * 3);
        col0 = tanhf(tp[0]);
        col1 = tanhf(tp[1]);
        col2 = tanhf(tp[2]);
    }
    float r0 = ref[0 * NPIX + p];
    float r1 = ref[1 * NPIX + p];
    float r2 = ref[2 * NPIX + p];
    float e0 = col0 - r0, e1 = col1 - r1, e2 = col2 - r2;
    float loss = e0 * e0 + e1 * e1 + e2 * e2;

    // ---- block reduce, one atomic per block ----
    for (int off = 32; off > 0; off >>= 1)
        loss += __shfl_down(loss, off, 64);
    if (lane == 0) wsum[w] = loss;
    __syncthreads();
    if (tid == 0)
        atomicAdd(out, wsum[0] + wsum[1] + wsum[2] + wsum[3]);
}

extern "C" void kernel_launch(void* const* d_in, const int* in_sizes, int n_in,
                              void* d_out, int out_size, void* d_ws, size_t ws_size,
                              hipStream_t stream) {
    const float* verts = (const float*)d_in[0];
    const float* tex   = (const float*)d_in[1];
    const float* ref   = (const float*)d_in[2];
    const int*   faces = (const int*)d_in[3];
    float* out = (float*)d_out;

    hipMemsetAsync(out, 0, sizeof(float), stream);
    render_loss<<<256, 256, 0, stream>>>(verts, faces, tex, ref, out);
}

// Round 15
// 16.461 us; speedup vs baseline: 3.9972x; 1.0614x over previous
//
#include <hip/hip_runtime.h>
#include <math.h>

#define NFACE 512
#define NVERT 642
#define NPIX  (256 * 256)
#define DXS   (2.0f / 256.0f)

// Camera constants (input-independent, folded from the reference):
#define EYEX 2.732f
#define EYEZ (-1.6728675276352845e-16f)
#define CC0  (6.123233995736766e-17f)

// Fused renderer, 256 blocks x 512 threads (8 waves -> 2 waves/SIMD for
// latency cover; R14 was 1 wave/SIMD and ~90% stalled). Block = 16x16 tile.
// Phase 1 (1 face/thread): exact corner-bound classify (reject/full/partial)
// + tile-level depth prune (M = min over full faces of dmax+md; dmin-md > M
// can never win the argmin — removes only reference-losing faces).
// Phase 2: list split across 8 waves (k%8==w), each wave covers ALL 256 px
// (4 px/thread) -> each record read once per CU, amortized over 4 px.
// Merge: [8][256] LDS u32-min. Pack (depth_bits & ~511) | face — order/
// partition-invariant, ties -> smaller face index (jnp.argmin first-index).
// Records: w_k = A_k*Py+B_k*Px+C_k (== ref w_k/denom, sign folded),
// w2 = 1-w0-w1; depth = DA*Py+DB*Px+DC; inside => depth>0 (camera z>1.73).
__global__ __launch_bounds__(512) void render_loss(
    const float* __restrict__ verts,   // (642,3)
    const int*   __restrict__ faces,   // (512,3)
    const float* __restrict__ tex,     // (512,4,4,4,3)
    const float* __restrict__ ref,     // (3,256,256)
    float* __restrict__ out)           // scalar (pre-zeroed)
{
    __shared__ float  sverts[NVERT * 3];
    __shared__ float4 sf0[NFACE];        // A0,B0,C0,A1   (epilogue)
    __shared__ float4 sf1[NFACE];        // B1,C1,DA,DB   (epilogue)
    __shared__ float4 flist[NFACE];      // full: DA,DB,DC,fid
    __shared__ float4 pl0[NFACE];        // partial: A0,B0,C0,A1
    __shared__ float4 pl1[NFACE];        // partial: B1,C1,DA,DB
    __shared__ float2 pld[NFACE];        // partial: DC,fid
    __shared__ unsigned marr[8][256];    // per-wave per-pixel packs
    __shared__ int   fcnt, pcnt;
    __shared__ unsigned Mu;
    __shared__ float wsum[8];

    int tid = threadIdx.x;
    if (tid == 0) { fcnt = 0; pcnt = 0; Mu = 0x7f800000u; }

    for (int k = tid; k < NVERT * 3; k += 512) sverts[k] = verts[k];
    __syncthreads();

    int tileX = (blockIdx.x & 15) << 4;
    int tileY = (blockIdx.x >> 4) << 4;
    float xlo = (tileX + 0.5f)  * DXS - 1.0f;
    float xhi = (tileX + 15.5f) * DXS - 1.0f;
    float yhi = 1.0f - (tileY + 0.5f)  * DXS;
    float ylo = 1.0f - (tileY + 15.5f) * DXS;

    // ---- phase 1a: setup + classify (1 face/thread, results in regs) ----
    float rc[9];         // A0,B0,C0,A1,B1,C1,DA,DB,DC
    int   rcls = 0;      // 0=rejected, 1=full, 2=partial
    float rdmn = 0.f;    // dmin - margin
    {
        int f = tid;
        float vx[3], vy[3], vz[3];
#pragma unroll
        for (int k = 0; k < 3; ++k) {
            int vi = faces[f * 3 + k];
            float px = sverts[vi * 3 + 0];
            float py = sverts[vi * 3 + 1];
            float pz = sverts[vi * 3 + 2];
            float dx = px - EYEX;
            float dz = pz - EYEZ;
            vx[k] = CC0 * dx + dz;
            vy[k] = py;
            vz[k] = -dx + CC0 * dz;
        }
        float ax = vx[0], ay = vy[0];
        float bx = vx[1], by = vy[1];
        float cx = vx[2], cy = vy[2];
        float denom = (bx - ax) * (cy - ay) - (by - ay) * (cx - ax);
        if (fabsf(denom) > 1e-8f) {
            float si = 1.0f / denom;              // sign folded
            float e0x = cx - bx, e0y = cy - by;
            float e1x = ax - cx, e1y = ay - cy;
            float A0 = e0x * si, B0 = -e0y * si, C0 = (e0y * bx - e0x * by) * si;
            float A1 = e1x * si, B1 = -e1y * si, C1 = (e1y * cx - e1x * cy) * si;
            float A2 = -(A0 + A1), B2 = -(B0 + B1), C2 = 1.0f - C0 - C1;
            float DA = A0 * vz[0] + A1 * vz[1] + A2 * vz[2];
            float DB = B0 * vz[0] + B1 * vz[1] + B2 * vz[2];
            float DC = C0 * vz[0] + C1 * vz[1] + C2 * vz[2];

            sf0[f] = make_float4(A0, B0, C0, A1);
            sf1[f] = make_float4(B1, C1, DA, DB);

            float bxmn = fminf(fminf(ax, bx), cx), bxmx = fmaxf(fmaxf(ax, bx), cx);
            float bymn = fminf(fminf(ay, by), cy), bymx = fmaxf(fmaxf(ay, by), cy);
            bool bboxout = (bxmn > xhi + 1e-5f) | (bxmx < xlo - 1e-5f) |
                           (bymn > yhi + 1e-5f) | (bymx < ylo - 1e-5f);
            if (!bboxout) {
                float wmx[3], wmn[3], mg[3];
                float As[3] = {A0, A1, A2}, Bs[3] = {B0, B1, B2}, Cs[3] = {C0, C1, C2};
#pragma unroll
                for (int k = 0; k < 3; ++k) {
                    float t1 = As[k] * ylo, t2 = As[k] * yhi;
                    float u1 = Bs[k] * xlo, u2 = Bs[k] * xhi;
                    wmx[k] = fmaxf(t1, t2) + fmaxf(u1, u2) + Cs[k];
                    wmn[k] = fminf(t1, t2) + fminf(u1, u2) + Cs[k];
                    mg[k]  = (fabsf(As[k]) + fabsf(Bs[k]) + fabsf(Cs[k])) * 2e-6f;
                }
                bool rej = (wmx[0] < -mg[0]) | (wmx[1] < -mg[1]) | (wmx[2] < -mg[2]);
                if (!rej) {
                    bool full = (wmn[0] > mg[0]) & (wmn[1] > mg[1]) & (wmn[2] > mg[2]);
                    float t1 = DA * ylo, t2 = DA * yhi;
                    float u1 = DB * xlo, u2 = DB * xhi;
                    float dmx = fmaxf(t1, t2) + fmaxf(u1, u2) + DC;
                    float dmn = fminf(t1, t2) + fminf(u1, u2) + DC;
                    float md  = (fabsf(DA) + fabsf(DB) + fabsf(DC)) * 2e-6f + 1e-4f;
                    rdmn = dmn - md;
                    rcls = full ? 1 : 2;
                    rc[0] = A0; rc[1] = B0; rc[2] = C0;
                    rc[3] = A1; rc[4] = B1; rc[5] = C1;
                    rc[6] = DA; rc[7] = DB; rc[8] = DC;
                    if (full) atomicMin(&Mu, __float_as_uint(dmx + md));
                }
            }
        }
    }
    __syncthreads();

    // ---- phase 1b: depth-pruned dense append ----
    float M = __uint_as_float(Mu);
    if (rcls != 0 && rdmn <= M) {
        float fb = __uint_as_float((unsigned)tid);
        if (rcls == 1) {
            int s = atomicAdd(&fcnt, 1);
            flist[s] = make_float4(rc[6], rc[7], rc[8], fb);
        } else {
            int s = atomicAdd(&pcnt, 1);
            pl0[s] = make_float4(rc[0], rc[1], rc[2], rc[3]);
            pl1[s] = make_float4(rc[4], rc[5], rc[6], rc[7]);
            pld[s] = make_float2(rc[8], fb);
        }
    }
    __syncthreads();
    int fc = fcnt, pc = pcnt;

    // ---- phase 2: wave w takes list entries k%8==w, covers ALL 256 px ----
    int lane = tid & 63;
    int w    = tid >> 6;
    int col   = lane & 15;
    int rbase = (lane >> 4) << 2;                 // rows rbase..rbase+3
    float Px  = (tileX + col + 0.5f) * DXS - 1.0f;
    float Py0 = 1.0f - (tileY + rbase + 0.5f) * DXS;

    unsigned pk0 = 0xFFFFFFFFu, pk1 = 0xFFFFFFFFu;
    unsigned pk2 = 0xFFFFFFFFu, pk3 = 0xFFFFFFFFu;

    for (int k = w; k < fc; k += 8) {
        float4 r = flist[k];
        float td = fmaf(r.y, Px, r.z);            // DB*Px + DC
        float d0 = fmaf(r.x, Py0, td);
        float d1 = fmaf(r.x, Py0 - DXS, td);
        float d2 = fmaf(r.x, Py0 - 2.0f * DXS, td);
        float d3 = fmaf(r.x, Py0 - 3.0f * DXS, td);
        unsigned fb = __float_as_uint(r.w);
        unsigned c0 = (__float_as_uint(d0) & 0xFFFFFE00u) | fb;
        unsigned c1 = (__float_as_uint(d1) & 0xFFFFFE00u) | fb;
        unsigned c2 = (__float_as_uint(d2) & 0xFFFFFE00u) | fb;
        unsigned c3 = (__float_as_uint(d3) & 0xFFFFFE00u) | fb;
        pk0 = pk0 < c0 ? pk0 : c0;
        pk1 = pk1 < c1 ? pk1 : c1;
        pk2 = pk2 < c2 ? pk2 : c2;
        pk3 = pk3 < c3 ? pk3 : c3;
    }

    for (int k = w; k < pc; k += 8) {
        float4 q0 = pl0[k];
        float4 q1 = pl1[k];
        float2 qd = pld[k];
        float t0 = fmaf(q0.y, Px, q0.z);          // B0*Px + C0
        float t1 = fmaf(q1.x, Px, q1.y);          // B1*Px + C1
        float td = fmaf(q1.w, Px, qd.x);          // DB*Px + DC
        unsigned fb = __float_as_uint(qd.y);
#pragma unroll
        for (int q = 0; q < 4; ++q) {
            float Py = Py0 - (float)q * DXS;
            float w0 = fmaf(q0.x, Py, t0);
            float w1 = fmaf(q0.w, Py, t1);
            float w2 = 1.0f - w0 - w1;
            float dp = fmaf(q1.z, Py, td);
            float mn = fminf(fminf(w0, w1), w2);
            unsigned cd = (__float_as_uint(dp) & 0xFFFFFE00u) | fb;
            cd = (mn >= 0.f) ? cd : 0xFFFFFFFFu;
            if (q == 0) pk0 = pk0 < cd ? pk0 : cd;
            if (q == 1) pk1 = pk1 < cd ? pk1 : cd;
            if (q == 2) pk2 = pk2 < cd ? pk2 : cd;
            if (q == 3) pk3 = pk3 < cd ? pk3 : cd;
        }
    }

    // ---- merge across 8 waves ----
    marr[w][(rbase + 0) * 16 + col] = pk0;
    marr[w][(rbase + 1) * 16 + col] = pk1;
    marr[w][(rbase + 2) * 16 + col] = pk2;
    marr[w][(rbase + 3) * 16 + col] = pk3;
    __syncthreads();

    // ---- phase 3: threads 0..255 finish pixel tid ----
    float loss = 0.f;
    if (tid < 256) {
        unsigned best = marr[0][tid];
#pragma unroll
        for (int ww = 1; ww < 8; ++ww) {
            unsigned m = marr[ww][tid];
            best = best < m ? best : m;
        }
        int i = tileX + (tid & 15);
        int j = tileY + (tid >> 4);
        float Pxe = (i + 0.5f) * DXS - 1.0f;
        float Pye = 1.0f - (j + 0.5f) * DXS;
        int p = j * 256 + i;
        float col0 = 0.f, col1 = 0.f, col2 = 0.f;
        if (best != 0xFFFFFFFFu) {
            int bf = (int)(best & 511u);
            float4 q0 = sf0[bf];
            float4 q1 = sf1[bf];
            float w0 = fmaf(q0.x, Pye, fmaf(q0.y, Pxe, q0.z));
            float w1 = fmaf(q0.w, Pye, fmaf(q1.x, Pxe, q1.y));
            float w2 = 1.0f - w0 - w1;
            int t0 = (int)rintf(w0 * 3.0f); t0 = t0 < 0 ? 0 : (t0 > 3 ? 3 : t0);
            int t1 = (int)rintf(w1 * 3.0f); t1 = t1 < 0 ? 0 : (t1 > 3 ? 3 : t1);
            int t2 = (int)rintf(w2 * 3.0f); t2 = t2 < 0 ? 0 : (t2 > 3 ? 3 : t2);
            const float* tp = tex + ((((bf * 4 + t0) * 4 + t1) * 4 + t2) * 3);
            col0 = tanhf(tp[0]);
            col1 = tanhf(tp[1]);
            col2 = tanhf(tp[2]);
        }
        float r0 = ref[0 * NPIX + p];
        float r1 = ref[1 * NPIX + p];
        float r2 = ref[2 * NPIX + p];
        float e0 = col0 - r0, e1 = col1 - r1, e2 = col2 - r2;
        loss = e0 * e0 + e1 * e1 + e2 * e2;
    }

    // ---- block reduce (8 waves), one atomic per block ----
    for (int off = 32; off > 0; off >>= 1)
        loss += __shfl_down(loss, off, 64);
    if (lane == 0) wsum[w] = loss;
    __syncthreads();
    if (tid == 0) {
        float s = wsum[0] + wsum[1] + wsum[2] + wsum[3]
                + wsum[4] + wsum[5] + wsum[6] + wsum[7];
        atomicAdd(out, s);
    }
}

extern "C" void kernel_launch(void* const* d_in, const int* in_sizes, int n_in,
                              void* d_out, int out_size, void* d_ws, size_t ws_size,
                              hipStream_t stream) {
    const float* verts = (const float*)d_in[0];
    const float* tex   = (const float*)d_in[1];
    const float* ref   = (const float*)d_in[2];
    const int*   faces = (const int*)d_in[3];
    float* out = (float*)d_out;

    hipMemsetAsync(out, 0, sizeof(float), stream);
    render_loss<<<256, 512, 0, stream>>>(verts, faces, tex, ref, out);
}

// Round 16
// 16.006 us; speedup vs baseline: 4.1109x; 1.0284x over previous
//
#include <hip/hip_runtime.h>
#include <math.h>

#define NFACE 512
#define NVERT 642
#define NPIX  (256 * 256)
#define DXS   (2.0f / 256.0f)

// Camera constants (input-independent, folded from the reference):
#define EYEX 2.732f
#define EYEZ (-1.6728675276352845e-16f)
#define CC0  (6.123233995736766e-17f)

// Fused renderer, single graph node. 256 blocks x 512 threads (2 waves/SIMD),
// block = 16x16 tile. Phase 1 (1 face/thread): exact corner-bound classify
// (reject/full/partial) + tile-level depth prune (M = min over full faces of
// dmax+md; dmin-md > M can never win the argmin — removes only
// reference-losing faces). Phase 2: list split across 8 waves (k%8==w), each
// wave covers ALL 256 px (4 px/thread). Merge: [8][256] LDS u32-min.
// Pack (depth_bits & ~511) | face — order/partition-invariant, ties ->
// smaller face index (jnp.argmin first-index).
// FINISH (no memset node, no same-address atomic tail): each block plain-
// stores bsum[blockIdx], __threadfence, atomicAdd(cntr,1); the block seeing
// old%256==255 (exactly one per 256 increments -> works from any persistent
// counter value, incl. the 0xAA poison; no reset needed) fences, reads the
// 256 partials via atomicAdd(+0.0f) (device-scope coherent, R6-proven),
// reduces, and plain-stores out[0] (idempotent across replays).
// Records: w_k = A_k*Py+B_k*Px+C_k (== ref w_k/denom, sign folded),
// w2 = 1-w0-w1; depth = DA*Py+DB*Px+DC; inside => depth>0 (camera z>1.73).
__global__ __launch_bounds__(512) void render_loss(
    const float* __restrict__ verts,   // (642,3)
    const int*   __restrict__ faces,   // (512,3)
    const float* __restrict__ tex,     // (512,4,4,4,3)
    const float* __restrict__ ref,     // (3,256,256)
    float* __restrict__ bsum,          // (256) per-block partials (d_ws)
    unsigned* __restrict__ cntr,       // completion counter (d_ws)
    float* __restrict__ out)           // scalar
{
    __shared__ float  sverts[NVERT * 3];
    __shared__ float4 sf0[NFACE];        // A0,B0,C0,A1   (epilogue)
    __shared__ float4 sf1[NFACE];        // B1,C1,DA,DB   (epilogue)
    __shared__ float4 flist[NFACE];      // full: DA,DB,DC,fid
    __shared__ float4 pl0[NFACE];        // partial: A0,B0,C0,A1
    __shared__ float4 pl1[NFACE];        // partial: B1,C1,DA,DB
    __shared__ float2 pld[NFACE];        // partial: DC,fid
    __shared__ unsigned marr[8][256];    // per-wave per-pixel packs
    __shared__ int   fcnt, pcnt;
    __shared__ unsigned Mu;
    __shared__ float wsum[8];
    __shared__ int sfinish;

    int tid = threadIdx.x;
    if (tid == 0) { fcnt = 0; pcnt = 0; Mu = 0x7f800000u; sfinish = 0; }

    for (int k = tid; k < NVERT * 3; k += 512) sverts[k] = verts[k];
    __syncthreads();

    int tileX = (blockIdx.x & 15) << 4;
    int tileY = (blockIdx.x >> 4) << 4;
    float xlo = (tileX + 0.5f)  * DXS - 1.0f;
    float xhi = (tileX + 15.5f) * DXS - 1.0f;
    float yhi = 1.0f - (tileY + 0.5f)  * DXS;
    float ylo = 1.0f - (tileY + 15.5f) * DXS;

    // ---- phase 1a: setup + classify (1 face/thread, results in regs) ----
    float rc[9];         // A0,B0,C0,A1,B1,C1,DA,DB,DC
    int   rcls = 0;      // 0=rejected, 1=full, 2=partial
    float rdmn = 0.f;    // dmin - margin
    {
        int f = tid;
        float vx[3], vy[3], vz[3];
#pragma unroll
        for (int k = 0; k < 3; ++k) {
            int vi = faces[f * 3 + k];
            float px = sverts[vi * 3 + 0];
            float py = sverts[vi * 3 + 1];
            float pz = sverts[vi * 3 + 2];
            float dx = px - EYEX;
            float dz = pz - EYEZ;
            vx[k] = CC0 * dx + dz;
            vy[k] = py;
            vz[k] = -dx + CC0 * dz;
        }
        float ax = vx[0], ay = vy[0];
        float bx = vx[1], by = vy[1];
        float cx = vx[2], cy = vy[2];
        float denom = (bx - ax) * (cy - ay) - (by - ay) * (cx - ax);
        if (fabsf(denom) > 1e-8f) {
            float si = 1.0f / denom;              // sign folded
            float e0x = cx - bx, e0y = cy - by;
            float e1x = ax - cx, e1y = ay - cy;
            float A0 = e0x * si, B0 = -e0y * si, C0 = (e0y * bx - e0x * by) * si;
            float A1 = e1x * si, B1 = -e1y * si, C1 = (e1y * cx - e1x * cy) * si;
            float A2 = -(A0 + A1), B2 = -(B0 + B1), C2 = 1.0f - C0 - C1;
            float DA = A0 * vz[0] + A1 * vz[1] + A2 * vz[2];
            float DB = B0 * vz[0] + B1 * vz[1] + B2 * vz[2];
            float DC = C0 * vz[0] + C1 * vz[1] + C2 * vz[2];

            sf0[f] = make_float4(A0, B0, C0, A1);
            sf1[f] = make_float4(B1, C1, DA, DB);

            float bxmn = fminf(fminf(ax, bx), cx), bxmx = fmaxf(fmaxf(ax, bx), cx);
            float bymn = fminf(fminf(ay, by), cy), bymx = fmaxf(fmaxf(ay, by), cy);
            bool bboxout = (bxmn > xhi + 1e-5f) | (bxmx < xlo - 1e-5f) |
                           (bymn > yhi + 1e-5f) | (bymx < ylo - 1e-5f);
            if (!bboxout) {
                float wmx[3], wmn[3], mg[3];
                float As[3] = {A0, A1, A2}, Bs[3] = {B0, B1, B2}, Cs[3] = {C0, C1, C2};
#pragma unroll
                for (int k = 0; k < 3; ++k) {
                    float t1 = As[k] * ylo, t2 = As[k] * yhi;
                    float u1 = Bs[k] * xlo, u2 = Bs[k] * xhi;
                    wmx[k] = fmaxf(t1, t2) + fmaxf(u1, u2) + Cs[k];
                    wmn[k] = fminf(t1, t2) + fminf(u1, u2) + Cs[k];
                    mg[k]  = (fabsf(As[k]) + fabsf(Bs[k]) + fabsf(Cs[k])) * 2e-6f;
                }
                bool rej = (wmx[0] < -mg[0]) | (wmx[1] < -mg[1]) | (wmx[2] < -mg[2]);
                if (!rej) {
                    bool full = (wmn[0] > mg[0]) & (wmn[1] > mg[1]) & (wmn[2] > mg[2]);
                    float t1 = DA * ylo, t2 = DA * yhi;
                    float u1 = DB * xlo, u2 = DB * xhi;
                    float dmx = fmaxf(t1, t2) + fmaxf(u1, u2) + DC;
                    float dmn = fminf(t1, t2) + fminf(u1, u2) + DC;
                    float md  = (fabsf(DA) + fabsf(DB) + fabsf(DC)) * 2e-6f + 1e-4f;
                    rdmn = dmn - md;
                    rcls = full ? 1 : 2;
                    rc[0] = A0; rc[1] = B0; rc[2] = C0;
                    rc[3] = A1; rc[4] = B1; rc[5] = C1;
                    rc[6] = DA; rc[7] = DB; rc[8] = DC;
                    if (full) atomicMin(&Mu, __float_as_uint(dmx + md));
                }
            }
        }
    }
    __syncthreads();

    // ---- phase 1b: depth-pruned dense append ----
    float M = __uint_as_float(Mu);
    if (rcls != 0 && rdmn <= M) {
        float fb = __uint_as_float((unsigned)tid);
        if (rcls == 1) {
            int s = atomicAdd(&fcnt, 1);
            flist[s] = make_float4(rc[6], rc[7], rc[8], fb);
        } else {
            int s = atomicAdd(&pcnt, 1);
            pl0[s] = make_float4(rc[0], rc[1], rc[2], rc[3]);
            pl1[s] = make_float4(rc[4], rc[5], rc[6], rc[7]);
            pld[s] = make_float2(rc[8], fb);
        }
    }
    __syncthreads();
    int fc = fcnt, pc = pcnt;

    // ---- phase 2: wave w takes list entries k%8==w, covers ALL 256 px ----
    int lane = tid & 63;
    int w    = tid >> 6;
    int col   = lane & 15;
    int rbase = (lane >> 4) << 2;                 // rows rbase..rbase+3
    float Px  = (tileX + col + 0.5f) * DXS - 1.0f;
    float Py0 = 1.0f - (tileY + rbase + 0.5f) * DXS;

    unsigned pk0 = 0xFFFFFFFFu, pk1 = 0xFFFFFFFFu;
    unsigned pk2 = 0xFFFFFFFFu, pk3 = 0xFFFFFFFFu;

    for (int k = w; k < fc; k += 8) {
        float4 r = flist[k];
        float td = fmaf(r.y, Px, r.z);            // DB*Px + DC
        float d0 = fmaf(r.x, Py0, td);
        float d1 = fmaf(r.x, Py0 - DXS, td);
        float d2 = fmaf(r.x, Py0 - 2.0f * DXS, td);
        float d3 = fmaf(r.x, Py0 - 3.0f * DXS, td);
        unsigned fb = __float_as_uint(r.w);
        unsigned c0 = (__float_as_uint(d0) & 0xFFFFFE00u) | fb;
        unsigned c1 = (__float_as_uint(d1) & 0xFFFFFE00u) | fb;
        unsigned c2 = (__float_as_uint(d2) & 0xFFFFFE00u) | fb;
        unsigned c3 = (__float_as_uint(d3) & 0xFFFFFE00u) | fb;
        pk0 = pk0 < c0 ? pk0 : c0;
        pk1 = pk1 < c1 ? pk1 : c1;
        pk2 = pk2 < c2 ? pk2 : c2;
        pk3 = pk3 < c3 ? pk3 : c3;
    }

    for (int k = w; k < pc; k += 8) {
        float4 q0 = pl0[k];
        float4 q1 = pl1[k];
        float2 qd = pld[k];
        float t0 = fmaf(q0.y, Px, q0.z);          // B0*Px + C0
        float t1 = fmaf(q1.x, Px, q1.y);          // B1*Px + C1
        float td = fmaf(q1.w, Px, qd.x);          // DB*Px + DC
        unsigned fb = __float_as_uint(qd.y);
#pragma unroll
        for (int q = 0; q < 4; ++q) {
            float Py = Py0 - (float)q * DXS;
            float w0 = fmaf(q0.x, Py, t0);
            float w1 = fmaf(q0.w, Py, t1);
            float w2 = 1.0f - w0 - w1;
            float dp = fmaf(q1.z, Py, td);
            float mn = fminf(fminf(w0, w1), w2);
            unsigned cd = (__float_as_uint(dp) & 0xFFFFFE00u) | fb;
            cd = (mn >= 0.f) ? cd : 0xFFFFFFFFu;
            if (q == 0) pk0 = pk0 < cd ? pk0 : cd;
            if (q == 1) pk1 = pk1 < cd ? pk1 : cd;
            if (q == 2) pk2 = pk2 < cd ? pk2 : cd;
            if (q == 3) pk3 = pk3 < cd ? pk3 : cd;
        }
    }

    // ---- merge across 8 waves ----
    marr[w][(rbase + 0) * 16 + col] = pk0;
    marr[w][(rbase + 1) * 16 + col] = pk1;
    marr[w][(rbase + 2) * 16 + col] = pk2;
    marr[w][(rbase + 3) * 16 + col] = pk3;
    __syncthreads();

    // ---- phase 3: threads 0..255 finish pixel tid ----
    float loss = 0.f;
    if (tid < 256) {
        unsigned best = marr[0][tid];
#pragma unroll
        for (int ww = 1; ww < 8; ++ww) {
            unsigned m = marr[ww][tid];
            best = best < m ? best : m;
        }
        int i = tileX + (tid & 15);
        int j = tileY + (tid >> 4);
        float Pxe = (i + 0.5f) * DXS - 1.0f;
        float Pye = 1.0f - (j + 0.5f) * DXS;
        int p = j * 256 + i;
        float col0 = 0.f, col1 = 0.f, col2 = 0.f;
        if (best != 0xFFFFFFFFu) {
            int bf = (int)(best & 511u);
            float4 q0 = sf0[bf];
            float4 q1 = sf1[bf];
            float w0 = fmaf(q0.x, Pye, fmaf(q0.y, Pxe, q0.z));
            float w1 = fmaf(q0.w, Pye, fmaf(q1.x, Pxe, q1.y));
            float w2 = 1.0f - w0 - w1;
            int t0 = (int)rintf(w0 * 3.0f); t0 = t0 < 0 ? 0 : (t0 > 3 ? 3 : t0);
            int t1 = (int)rintf(w1 * 3.0f); t1 = t1 < 0 ? 0 : (t1 > 3 ? 3 : t1);
            int t2 = (int)rintf(w2 * 3.0f); t2 = t2 < 0 ? 0 : (t2 > 3 ? 3 : t2);
            const float* tp = tex + ((((bf * 4 + t0) * 4 + t1) * 4 + t2) * 3);
            col0 = tanhf(tp[0]);
            col1 = tanhf(tp[1]);
            col2 = tanhf(tp[2]);
        }
        float r0 = ref[0 * NPIX + p];
        float r1 = ref[1 * NPIX + p];
        float r2 = ref[2 * NPIX + p];
        float e0 = col0 - r0, e1 = col1 - r1, e2 = col2 - r2;
        loss = e0 * e0 + e1 * e1 + e2 * e2;
    }

    // ---- block reduce (8 waves) ----
    for (int off = 32; off > 0; off >>= 1)
        loss += __shfl_down(loss, off, 64);
    if (lane == 0) wsum[w] = loss;
    __syncthreads();

    // ---- store partial, count completion, elected finisher reduces ----
    if (tid == 0) {
        bsum[blockIdx.x] = wsum[0] + wsum[1] + wsum[2] + wsum[3]
                         + wsum[4] + wsum[5] + wsum[6] + wsum[7];
        __threadfence();
        unsigned old = atomicAdd(cntr, 1u);
        if ((old & 255u) == 255u) sfinish = 1;
    }
    __syncthreads();
    if (sfinish) {
        __threadfence();
        float v = (tid < 256) ? atomicAdd(&bsum[tid], 0.0f) : 0.0f;
        for (int off = 32; off > 0; off >>= 1)
            v += __shfl_down(v, off, 64);
        if (lane == 0) wsum[w] = v;
        __syncthreads();
        if (tid == 0)
            out[0] = wsum[0] + wsum[1] + wsum[2] + wsum[3]
                   + wsum[4] + wsum[5] + wsum[6] + wsum[7];
    }
}

extern "C" void kernel_launch(void* const* d_in, const int* in_sizes, int n_in,
                              void* d_out, int out_size, void* d_ws, size_t ws_size,
                              hipStream_t stream) {
    const float* verts = (const float*)d_in[0];
    const float* tex   = (const float*)d_in[1];
    const float* ref   = (const float*)d_in[2];
    const int*   faces = (const int*)d_in[3];
    float* out  = (float*)d_out;
    float* bsum = (float*)d_ws;                    // 256 floats
    unsigned* cntr = (unsigned*)((float*)d_ws + 256);

    render_loss<<<256, 512, 0, stream>>>(verts, faces, tex, ref, bsum, cntr, out);
}